// Round 2
// 155.815 us; speedup vs baseline: 1.0060x; 1.0060x over previous
//
#include <hip/hip_runtime.h>
#include <cstdint>

typedef _Float16 f16;
typedef _Float16 f16x2 __attribute__((ext_vector_type(2)));
typedef _Float16 f16x8 __attribute__((ext_vector_type(8)));
typedef float    f32x4 __attribute__((ext_vector_type(4)));

static __device__ __forceinline__ uint32_t pack2(float x, float y) {
    f16 hx = (f16)x, hy = (f16)y;
    uint32_t ux = __builtin_bit_cast(unsigned short, hx);
    uint32_t uy = __builtin_bit_cast(unsigned short, hy);
    return ux | (uy << 16);
}

// ---------------------------------------------------------------------------
// Kernel 1: A (f32, [B][M][N], re & im planes) -> At (f16, [plane][B][N][M])
// 64x64 tiles through LDS. grid = B*16*2, block = 256.  (HBM-roofline.)
// ---------------------------------------------------------------------------
__global__ __launch_bounds__(256) void k_transpose(const float* __restrict__ Are,
                                                   const float* __restrict__ Aim,
                                                   f16* __restrict__ At) {
    const int tid = threadIdx.x;
    int bid = blockIdx.x;
    const int plane = bid & 1; bid >>= 1;
    const int b = bid >> 4;
    const int tile = bid & 15;
    const int m0 = (tile >> 2) * 64, n0 = (tile & 3) * 64;

    const float* src = (plane ? Aim : Are) + (size_t)b * 65536;
    f16* dst = At + (size_t)plane * 16777216 + (size_t)b * 65536;

    __shared__ uint32_t lt[64][33];   // [n][m-pair], +1 pad

    const int rp = tid >> 3;          // row-pair 0..31  (m = m0 + 2*rp, +1)
    const int c0 = (tid & 7) * 8;     // col start (n offset)
    const float* s0 = src + (size_t)(m0 + rp * 2) * 256 + n0 + c0;
    float4 x0 = *(const float4*)(s0);
    float4 x1 = *(const float4*)(s0 + 4);
    float4 y0 = *(const float4*)(s0 + 256);
    float4 y1 = *(const float4*)(s0 + 260);

    lt[c0 + 0][rp] = pack2(x0.x, y0.x);
    lt[c0 + 1][rp] = pack2(x0.y, y0.y);
    lt[c0 + 2][rp] = pack2(x0.z, y0.z);
    lt[c0 + 3][rp] = pack2(x0.w, y0.w);
    lt[c0 + 4][rp] = pack2(x1.x, y1.x);
    lt[c0 + 5][rp] = pack2(x1.y, y1.y);
    lt[c0 + 6][rp] = pack2(x1.z, y1.z);
    lt[c0 + 7][rp] = pack2(x1.w, y1.w);

    __syncthreads();

    const int n = tid >> 2, mq = tid & 3;
    uint32_t u[8];
#pragma unroll
    for (int j = 0; j < 8; ++j) u[j] = lt[n][mq * 8 + j];
    f16* o = dst + (size_t)(n0 + n) * 256 + m0 + mq * 16;
    *(uint4*)(void*)(o)     = make_uint4(u[0], u[1], u[2], u[3]);
    *(uint4*)(void*)(o + 8) = make_uint4(u[4], u[5], u[6], u[7]);
}

// ---------------------------------------------------------------------------
// Kernel 2: AhA[b][n][c] = sum_m conj(A[m][n]) A[m][c].  MFMA 16x16x32 f16.
// grid = B*4 (2x2 quadrants), block = 256 (4 waves, each a 64x64 sub-tile).
// ---------------------------------------------------------------------------
__global__ __launch_bounds__(256, 2) void k_gemm(const f16* __restrict__ At,
                                                 f16* __restrict__ AhAre,
                                                 f16* __restrict__ AhAim) {
    const int tid = threadIdx.x;
    const int bid = blockIdx.x;
    const int b = bid >> 2;
    const int q = bid & 3;
    const int n0 = (q >> 1) * 128, j0 = (q & 1) * 128;

    const f16* Ar = At + (size_t)b * 65536;
    const f16* Ai = At + 16777216 + (size_t)b * 65536;

    __shared__ __align__(16) f16 ls[4][128 * 32];  // [Are_n, Aim_n, Are_j, Aim_j]

    const int l = tid & 63, w = tid >> 6;
    const int wr = w >> 1, wc = w & 1;
    const int lr = l & 15, lk = l >> 4;

    f32x4 aR[4][4], aI[4][4];
#pragma unroll
    for (int i = 0; i < 4; ++i)
#pragma unroll
        for (int j = 0; j < 4; ++j) { aR[i][j] = (f32x4)0.0f; aI[i][j] = (f32x4)0.0f; }

    for (int m0 = 0; m0 < 256; m0 += 32) {
        __syncthreads();
        // stage 4 tiles: [row(128)][k-slot(4) of 8 f16], XOR-swizzled slots
#pragma unroll
        for (int t = 0; t < 4; ++t) {
            const f16* src = (t & 1 ? Ai : Ar) + (size_t)(t < 2 ? n0 : j0) * 256 + m0;
#pragma unroll
            for (int cc = 0; cc < 2; ++cc) {
                int chunk = tid * 2 + cc;              // 0..511
                int r = chunk >> 2, s = chunk & 3;
                int klog = s ^ ((r >> 1) & 3);
                uint4 g = *(const uint4*)(src + (size_t)r * 256 + klog * 8);
                *(uint4*)(&ls[t][r * 32 + s * 8]) = g;
            }
        }
        __syncthreads();

        f16x8 bre[4], bim[4];
#pragma unroll
        for (int j = 0; j < 4; ++j) {
            int rloc = wc * 64 + j * 16 + lr;
            int s1 = lk ^ ((rloc >> 1) & 3);
            bre[j] = *(const f16x8*)(&ls[2][rloc * 32 + s1 * 8]);
            bim[j] = *(const f16x8*)(&ls[3][rloc * 32 + s1 * 8]);
        }
#pragma unroll
        for (int i = 0; i < 4; ++i) {
            int rloc = wr * 64 + i * 16 + lr;
            int s1 = lk ^ ((rloc >> 1) & 3);
            f16x8 are = *(const f16x8*)(&ls[0][rloc * 32 + s1 * 8]);
            uint4 un  = *(const uint4*)(&ls[1][rloc * 32 + s1 * 8]);
            f16x8 aim = __builtin_bit_cast(f16x8, un);
            uint4 nn = make_uint4(un.x ^ 0x80008000u, un.y ^ 0x80008000u,
                                  un.z ^ 0x80008000u, un.w ^ 0x80008000u);
            f16x8 nai = __builtin_bit_cast(f16x8, nn);
#pragma unroll
            for (int j = 0; j < 4; ++j) {
                aR[i][j] = __builtin_amdgcn_mfma_f32_16x16x32_f16(are, bre[j], aR[i][j], 0, 0, 0);
                aR[i][j] = __builtin_amdgcn_mfma_f32_16x16x32_f16(aim, bim[j], aR[i][j], 0, 0, 0);
                aI[i][j] = __builtin_amdgcn_mfma_f32_16x16x32_f16(are, bim[j], aI[i][j], 0, 0, 0);
                aI[i][j] = __builtin_amdgcn_mfma_f32_16x16x32_f16(nai, bre[j], aI[i][j], 0, 0, 0);
            }
        }
    }

    f16* oR = AhAre + (size_t)b * 65536;
    f16* oI = AhAim + (size_t)b * 65536;
#pragma unroll
    for (int i = 0; i < 4; ++i)
#pragma unroll
        for (int j = 0; j < 4; ++j)
#pragma unroll
            for (int r = 0; r < 4; ++r) {
                int n = n0 + wr * 64 + i * 16 + lk * 4 + r;
                int c = j0 + wc * 64 + j * 16 + lr;
                oR[(size_t)n * 256 + c] = (f16)aR[i][j][r];
                oI[(size_t)n * 256 + c] = (f16)aI[i][j][r];
            }
}

// ---------------------------------------------------------------------------
// Kernel 3: power iteration on MFMA, DEFERRED NORMALIZATION (stable form).
// One 1024-thread block (16 waves) per batch; wave g owns rows 16g..16g+15.
// A-op fragments pinned in AGPRs.  Iterations 1,2 are synchronous (seed
// n_1 = n_2 = 1 exactly); iterations t>=3 use ONE barrier each with scale
//   s_t = n_{t-2} / (e_{t-1} * n_{t-1}),  n_{t-1} = e_{t-1} * s_{t-1}
// (lambda-estimate from the previous step => n_t == 1 in steady state; all
// recurrence roots at 0 -> no oscillation, f16-safe).  The e_{t-1} reduce
// runs in the shadow of iteration t's MFMA chain.  Final eig is exact:
//   eig = ||y_T|| / n_{T-1}.
// ---------------------------------------------------------------------------
static __device__ __forceinline__ float4 matvec(const f16x8 (&afr)[16],
                                                const f16* __restrict__ vs, int h) {
    f32x4 P0 = (f32x4)0.0f, P1 = (f32x4)0.0f;
#pragma unroll
    for (int c = 0; c < 16; ++c) {
        // unconditional load: lanes sel>=2 fetch valid-but-unused data; the
        // resulting garbage in MFMA cols 2..15 is masked out downstream.
        f16x8 bf = *(const f16x8*)(vs + 32 * c + 8 * h);
        if (c & 1) P1 = __builtin_amdgcn_mfma_f32_16x16x32_f16(afr[c], bf, P1, 0, 0, 0);
        else       P0 = __builtin_amdgcn_mfma_f32_16x16x32_f16(afr[c], bf, P0, 0, 0, 0);
    }
    return make_float4(P0[0] + P1[0], P0[1] + P1[1], P0[2] + P1[2], P0[3] + P1[3]);
}

__global__ __launch_bounds__(1024, 4) void k_power(const f16* __restrict__ AhAre,
                                                   const f16* __restrict__ AhAim,
                                                   const float* __restrict__ vre,
                                                   const float* __restrict__ vim,
                                                   const int* __restrict__ pniter,
                                                   float* __restrict__ out) {
    const int tid = threadIdx.x;
    const int b = blockIdx.x;
    const int l = tid & 63;            // lane
    const int g = tid >> 6;            // wave 0..15
    const int sel = l & 15;            // A-row-within-group / B-col
    const int h = l >> 4;              // k-slot 0..3

    __shared__ __align__(16) f16 v0h[2][512];   // [buf][ vr ; -vi ]
    __shared__ __align__(16) f16 v1h[2][512];   // [buf][ vi ;  vr ]
    __shared__ __align__(16) float part[2][16];

    // ---- load A fragments: row m = 16g+sel, chunk c covers k=32c+8h..+7
    const int m = 16 * g + sel;
    const f16* bR = AhAre + (size_t)b * 65536 + (size_t)m * 256 + 8 * h;
    const f16* bI = AhAim + (size_t)b * 65536 + (size_t)m * 256 + 8 * h;
    f16x8 afr[16];
#pragma unroll
    for (int c = 0; c < 8; ++c) {
        afr[c]     = *(const f16x8*)(bR + 32 * c);
        afr[8 + c] = *(const f16x8*)(bI + 32 * c);
    }
#pragma unroll
    for (int c = 0; c < 16; ++c) asm volatile("" : "+a"(afr[c]));

    if (tid < 256) {
        float xr = vre[b * 256 + tid], xi = vim[b * 256 + tid];
        v0h[0][tid]       = (f16)xr;
        v0h[0][256 + tid] = (f16)(-xi);
        v1h[0][tid]       = (f16)xi;
        v1h[0][256 + tid] = (f16)xr;
    }
    __syncthreads();

    const int niter = *pniter;
    const f16* vsel = (sel == 0) ? &v0h[0][0] : &v1h[0][0];

    float eig = 0.0f;

    auto npart = [&](int wb, const float4& y) {
        float s_ = 0.0f;
        if (sel < 2) s_ = y.x * y.x + y.y * y.y + y.z * y.z + y.w * y.w;
        s_ += __shfl_xor(s_, 1, 64);
        s_ += __shfl_xor(s_, 16, 64);
        s_ += __shfl_xor(s_, 32, 64);
        if (l == 0) part[wb][g] = s_;
    };
    auto vwrite = [&](int wb, const float4& y, float sc) {
        if (sel < 2) {
            uint32_t w0 = pack2(y.x * sc, y.y * sc);
            uint32_t w1 = pack2(y.z * sc, y.w * sc);
            int m0 = 16 * g + 4 * h;
            if (sel == 0) {
                *(uint2*)(void*)(&v0h[wb][m0])       = make_uint2(w0, w1);
                *(uint2*)(void*)(&v1h[wb][256 + m0]) = make_uint2(w0, w1);
            } else {
                *(uint2*)(void*)(&v1h[wb][m0])       = make_uint2(w0, w1);
                *(uint2*)(void*)(&v0h[wb][256 + m0]) =
                    make_uint2(w0 ^ 0x80008000u, w1 ^ 0x80008000u);
            }
        }
    };
    auto psum = [&](int rb) -> float {
        float4 q0 = *(const float4*)(&part[rb][0]);
        float4 q1 = *(const float4*)(&part[rb][4]);
        float4 q2 = *(const float4*)(&part[rb][8]);
        float4 q3 = *(const float4*)(&part[rb][12]);
        return (q0.x + q0.y + q0.z + q0.w) + (q1.x + q1.y + q1.z + q1.w)
             + (q2.x + q2.y + q2.z + q2.w) + (q3.x + q3.y + q3.z + q3.w);
    };

    float sc_m1 = 1.0f;   // s_{t-1}
    float nm2   = 1.0f;   // n_{t-2}

    // ---- peeled iteration 1 (synchronous): u_1 = y_1/e_1, n_1 = 1 ----
    if (niter >= 1) {
        float4 y = matvec(afr, vsel, h);
        npart(1, y);
        __syncthreads();
        float e1v = sqrtf(psum(1));
        float sc  = __builtin_amdgcn_rcpf(e1v + 1e-6f);
        vwrite(1, y, sc);
        eig = e1v;
        __syncthreads();
    }
    // ---- peeled iteration 2 (synchronous): u_2 = y_2/e_2, n_2 = 1 ----
    if (niter >= 2) {
        float4 y = matvec(afr, vsel + 512, h);
        npart(0, y);
        __syncthreads();
        float e2v = sqrtf(psum(0));
        float sc  = __builtin_amdgcn_rcpf(e2v + 1e-6f);
        vwrite(0, y, sc);
        eig = e2v;
        sc_m1 = sc;   // s_2
        nm2   = 1.0f; // n_1
        __syncthreads();
    }

    // ---- pipelined iterations 3..niter: one barrier each ----
    int wr = 0;
    for (int t = 3; t <= niter; ++t) {
        const int rd = wr;    // buffer holding u_{t-1}, part[rd] = q_{t-1}
        wr ^= 1;
        float q   = psum(rd);                                  // ||y_{t-1}||^2
        float e1v = __builtin_amdgcn_sqrtf(q);                 // e_{t-1}
        float nm1 = e1v * sc_m1;                               // n_{t-1}
        float sc  = nm2 * __builtin_amdgcn_rcpf(e1v * nm1 + 1e-12f);  // s_t
        float4 y  = matvec(afr, vsel + (size_t)rd * 512, h);   // y_t
        vwrite(wr, y, sc);
        npart(wr, y);
        nm2 = nm1; sc_m1 = sc;
        __syncthreads();
    }

    // ---- epilogue: exact eig = ||y_T|| / n_{T-1}
    if (niter >= 3) {
        float qT = psum(wr);
        eig = sqrtf(qT) / (nm2 + 1e-12f);
    }
    if (tid == 0) out[b] = eig;
}

extern "C" void kernel_launch(void* const* d_in, const int* in_sizes, int n_in,
                              void* d_out, int out_size, void* d_ws, size_t ws_size,
                              hipStream_t stream) {
    const float* Are = (const float*)d_in[0];
    const float* Aim = (const float*)d_in[1];
    const float* vre = (const float*)d_in[2];
    const float* vim = (const float*)d_in[3];
    const int* niter = (const int*)d_in[4];
    float* out = (float*)d_out;

    f16* At    = (f16*)d_ws;                                            // 64 MB
    f16* AhAre = (f16*)((char*)d_ws + (size_t)64 * 1024 * 1024);        // 32 MB
    f16* AhAim = (f16*)((char*)d_ws + (size_t)96 * 1024 * 1024);        // 32 MB

    k_transpose<<<dim3(8192), dim3(256), 0, stream>>>(Are, Aim, At);
    k_gemm<<<dim3(1024), dim3(256), 0, stream>>>(At, AhAre, AhAim);
    k_power<<<dim3(256), dim3(1024), 0, stream>>>(AhAre, AhAim, vre, vim, niter, out);
}

// Round 4
// 143.961 us; speedup vs baseline: 1.0888x; 1.0823x over previous
//
#include <hip/hip_runtime.h>
#include <cstdint>

typedef _Float16 f16;
typedef _Float16 f16x2 __attribute__((ext_vector_type(2)));
typedef _Float16 f16x8 __attribute__((ext_vector_type(8)));
typedef float    f32x4 __attribute__((ext_vector_type(4)));

static __device__ __forceinline__ uint32_t pack2(float x, float y) {
    f16 hx = (f16)x, hy = (f16)y;
    uint32_t ux = __builtin_bit_cast(unsigned short, hx);
    uint32_t uy = __builtin_bit_cast(unsigned short, hy);
    return ux | (uy << 16);
}

// ---------------------------------------------------------------------------
// Kernel 1: A (f32, [B][M][N], re & im planes) -> At (f16, [plane][B][N][M])
// 64x64 tiles through LDS. grid = B*16*2, block = 256.  (HBM-roofline.)
// ---------------------------------------------------------------------------
__global__ __launch_bounds__(256) void k_transpose(const float* __restrict__ Are,
                                                   const float* __restrict__ Aim,
                                                   f16* __restrict__ At) {
    const int tid = threadIdx.x;
    int bid = blockIdx.x;
    const int plane = bid & 1; bid >>= 1;
    const int b = bid >> 4;
    const int tile = bid & 15;
    const int m0 = (tile >> 2) * 64, n0 = (tile & 3) * 64;

    const float* src = (plane ? Aim : Are) + (size_t)b * 65536;
    f16* dst = At + (size_t)plane * 16777216 + (size_t)b * 65536;

    __shared__ uint32_t lt[64][33];   // [n][m-pair], +1 pad

    const int rp = tid >> 3;          // row-pair 0..31  (m = m0 + 2*rp, +1)
    const int c0 = (tid & 7) * 8;     // col start (n offset)
    const float* s0 = src + (size_t)(m0 + rp * 2) * 256 + n0 + c0;
    float4 x0 = *(const float4*)(s0);
    float4 x1 = *(const float4*)(s0 + 4);
    float4 y0 = *(const float4*)(s0 + 256);
    float4 y1 = *(const float4*)(s0 + 260);

    lt[c0 + 0][rp] = pack2(x0.x, y0.x);
    lt[c0 + 1][rp] = pack2(x0.y, y0.y);
    lt[c0 + 2][rp] = pack2(x0.z, y0.z);
    lt[c0 + 3][rp] = pack2(x0.w, y0.w);
    lt[c0 + 4][rp] = pack2(x1.x, y1.x);
    lt[c0 + 5][rp] = pack2(x1.y, y1.y);
    lt[c0 + 6][rp] = pack2(x1.z, y1.z);
    lt[c0 + 7][rp] = pack2(x1.w, y1.w);

    __syncthreads();

    const int n = tid >> 2, mq = tid & 3;
    uint32_t u[8];
#pragma unroll
    for (int j = 0; j < 8; ++j) u[j] = lt[n][mq * 8 + j];
    f16* o = dst + (size_t)(n0 + n) * 256 + m0 + mq * 16;
    *(uint4*)(void*)(o)     = make_uint4(u[0], u[1], u[2], u[3]);
    *(uint4*)(void*)(o + 8) = make_uint4(u[4], u[5], u[6], u[7]);
}

// ---------------------------------------------------------------------------
// Kernel 2: AhA[b][n][c] = sum_m conj(A[m][n]) A[m][c].  MFMA 16x16x32 f16.
// HERMITIAN: only 3 quadrants computed (grid = B*3).  qq==1 (rows 0-127,
// cols 128-255) mirrors its tile to quadrant (128-255, 0-127) via an LDS
// retranspose: Re copied, Im negated.  (MFMA accumulation order for (n,c)
// and (c,n) is identical, so the mirror is numerically exact.)
// XCD-aware block swizzle: the 3 blocks of a batch share one At slice.
// ---------------------------------------------------------------------------
__global__ __launch_bounds__(256, 2) void k_gemm(const f16* __restrict__ At,
                                                 f16* __restrict__ AhAre,
                                                 f16* __restrict__ AhAim) {
    const int tid = threadIdx.x;
    // bijective XCD swizzle for nwg=768 (768 % 8 == 0): chunk 96 per XCD
    int bid0 = blockIdx.x;
    int bid = (bid0 & 7) * 96 + (bid0 >> 3);
    const int b  = bid / 3;
    const int qq = bid - b * 3;                 // 0,1,2
    const int n0 = (qq == 2) ? 128 : 0;
    const int j0 = (qq >= 1) ? 128 : 0;

    const f16* Ar = At + (size_t)b * 65536;
    const f16* Ai = At + 16777216 + (size_t)b * 65536;

    __shared__ __align__(16) f16 ls[4][128 * 32];  // [Are_n, Aim_n, Are_j, Aim_j]

    const int l = tid & 63, w = tid >> 6;
    const int wr = w >> 1, wc = w & 1;
    const int lr = l & 15, lk = l >> 4;

    f32x4 aR[4][4], aI[4][4];
#pragma unroll
    for (int i = 0; i < 4; ++i)
#pragma unroll
        for (int j = 0; j < 4; ++j) { aR[i][j] = (f32x4)0.0f; aI[i][j] = (f32x4)0.0f; }

    for (int m0 = 0; m0 < 256; m0 += 32) {
        __syncthreads();
        // stage 4 tiles: [row(128)][k-slot(4) of 8 f16], XOR-swizzled slots
#pragma unroll
        for (int t = 0; t < 4; ++t) {
            const f16* src = (t & 1 ? Ai : Ar) + (size_t)(t < 2 ? n0 : j0) * 256 + m0;
#pragma unroll
            for (int cc = 0; cc < 2; ++cc) {
                int chunk = tid * 2 + cc;              // 0..511
                int r = chunk >> 2, s = chunk & 3;
                int klog = s ^ ((r >> 1) & 3);
                uint4 g = *(const uint4*)(src + (size_t)r * 256 + klog * 8);
                *(uint4*)(&ls[t][r * 32 + s * 8]) = g;
            }
        }
        __syncthreads();

        f16x8 bre[4], bim[4];
#pragma unroll
        for (int j = 0; j < 4; ++j) {
            int rloc = wc * 64 + j * 16 + lr;
            int s1 = lk ^ ((rloc >> 1) & 3);
            bre[j] = *(const f16x8*)(&ls[2][rloc * 32 + s1 * 8]);
            bim[j] = *(const f16x8*)(&ls[3][rloc * 32 + s1 * 8]);
        }
#pragma unroll
        for (int i = 0; i < 4; ++i) {
            int rloc = wr * 64 + i * 16 + lr;
            int s1 = lk ^ ((rloc >> 1) & 3);
            f16x8 are = *(const f16x8*)(&ls[0][rloc * 32 + s1 * 8]);
            uint4 un  = *(const uint4*)(&ls[1][rloc * 32 + s1 * 8]);
            f16x8 aim = __builtin_bit_cast(f16x8, un);
            uint4 nn = make_uint4(un.x ^ 0x80008000u, un.y ^ 0x80008000u,
                                  un.z ^ 0x80008000u, un.w ^ 0x80008000u);
            f16x8 nai = __builtin_bit_cast(f16x8, nn);
#pragma unroll
            for (int j = 0; j < 4; ++j) {
                aR[i][j] = __builtin_amdgcn_mfma_f32_16x16x32_f16(are, bre[j], aR[i][j], 0, 0, 0);
                aR[i][j] = __builtin_amdgcn_mfma_f32_16x16x32_f16(aim, bim[j], aR[i][j], 0, 0, 0);
                aI[i][j] = __builtin_amdgcn_mfma_f32_16x16x32_f16(are, bim[j], aI[i][j], 0, 0, 0);
                aI[i][j] = __builtin_amdgcn_mfma_f32_16x16x32_f16(nai, bre[j], aI[i][j], 0, 0, 0);
            }
        }
    }

    f16* oR = AhAre + (size_t)b * 65536;
    f16* oI = AhAim + (size_t)b * 65536;
#pragma unroll
    for (int i = 0; i < 4; ++i)
#pragma unroll
        for (int j = 0; j < 4; ++j)
#pragma unroll
            for (int r = 0; r < 4; ++r) {
                int n = n0 + wr * 64 + i * 16 + lk * 4 + r;
                int c = j0 + wc * 64 + j * 16 + lr;
                oR[(size_t)n * 256 + c] = (f16)aR[i][j][r];
                oI[(size_t)n * 256 + c] = (f16)aI[i][j][r];
            }

    // ---- Hermitian mirror: quadrant (128+jj, nn) = conj(our (nn, 128+jj)) ----
    // Each thread copies 64 f16 of its row-half as 8 x uint4 (uint4 = 8 f16!).
    if (qq == 1) {
        f16* lsm = &ls[0][0];                      // reuse 32 KB as [128][128]
        const int jj_out = tid >> 1, hf = (tid & 1) * 64;

        // Re plane: copy
        __syncthreads();
#pragma unroll
        for (int i = 0; i < 4; ++i)
#pragma unroll
            for (int j = 0; j < 4; ++j)
#pragma unroll
                for (int r = 0; r < 4; ++r) {
                    int nn = wr * 64 + i * 16 + lk * 4 + r;
                    int jj = wc * 64 + j * 16 + lr;
                    lsm[jj * 128 + nn] = (f16)aR[i][j][r];
                }
        __syncthreads();
        {
            const f16* srow = lsm + jj_out * 128 + hf;
            f16* drow = oR + (size_t)(128 + jj_out) * 256 + hf;
#pragma unroll
            for (int ch = 0; ch < 8; ++ch)
                *(uint4*)(void*)(drow + ch * 8) = *(const uint4*)(srow + ch * 8);
        }
        __syncthreads();

        // Im plane: negate
#pragma unroll
        for (int i = 0; i < 4; ++i)
#pragma unroll
            for (int j = 0; j < 4; ++j)
#pragma unroll
                for (int r = 0; r < 4; ++r) {
                    int nn = wr * 64 + i * 16 + lk * 4 + r;
                    int jj = wc * 64 + j * 16 + lr;
                    lsm[jj * 128 + nn] = (f16)(-aI[i][j][r]);
                }
        __syncthreads();
        {
            const f16* srow = lsm + jj_out * 128 + hf;
            f16* drow = oI + (size_t)(128 + jj_out) * 256 + hf;
#pragma unroll
            for (int ch = 0; ch < 8; ++ch)
                *(uint4*)(void*)(drow + ch * 8) = *(const uint4*)(srow + ch * 8);
        }
    }
}

// ---------------------------------------------------------------------------
// Kernel 3: power iteration on MFMA, DEFERRED NORMALIZATION (stable form).
// One 1024-thread block (16 waves) per batch; wave g owns rows 16g..16g+15.
// A-op fragments pinned in AGPRs (60 VGPR + 64 AGPR = 124 <= 128: do NOT
// add register pressure here, 16 waves/CU is the occupancy knee).
// s_setprio(1) wraps the MFMA chain.
// ---------------------------------------------------------------------------
static __device__ __forceinline__ float4 matvec(const f16x8 (&afr)[16],
                                                const f16* __restrict__ vs, int h) {
    f32x4 P0 = (f32x4)0.0f, P1 = (f32x4)0.0f;
    __builtin_amdgcn_s_setprio(1);
#pragma unroll
    for (int c = 0; c < 16; ++c) {
        f16x8 bf = *(const f16x8*)(vs + 32 * c + 8 * h);
        if (c & 1) P1 = __builtin_amdgcn_mfma_f32_16x16x32_f16(afr[c], bf, P1, 0, 0, 0);
        else       P0 = __builtin_amdgcn_mfma_f32_16x16x32_f16(afr[c], bf, P0, 0, 0, 0);
    }
    __builtin_amdgcn_s_setprio(0);
    return make_float4(P0[0] + P1[0], P0[1] + P1[1], P0[2] + P1[2], P0[3] + P1[3]);
}

__global__ __launch_bounds__(1024, 4) void k_power(const f16* __restrict__ AhAre,
                                                   const f16* __restrict__ AhAim,
                                                   const float* __restrict__ vre,
                                                   const float* __restrict__ vim,
                                                   const int* __restrict__ pniter,
                                                   float* __restrict__ out) {
    const int tid = threadIdx.x;
    const int b = blockIdx.x;
    const int l = tid & 63;            // lane
    const int g = tid >> 6;            // wave 0..15
    const int sel = l & 15;            // A-row-within-group / B-col
    const int h = l >> 4;              // k-slot 0..3

    __shared__ __align__(16) f16 v0h[2][512];   // [buf][ vr ; -vi ]
    __shared__ __align__(16) f16 v1h[2][512];   // [buf][ vi ;  vr ]
    __shared__ __align__(16) float part[2][16];

    // ---- load A fragments: row m = 16g+sel, chunk c covers k=32c+8h..+7
    const int m = 16 * g + sel;
    const f16* bR = AhAre + (size_t)b * 65536 + (size_t)m * 256 + 8 * h;
    const f16* bI = AhAim + (size_t)b * 65536 + (size_t)m * 256 + 8 * h;
    f16x8 afr[16];
#pragma unroll
    for (int c = 0; c < 8; ++c) {
        afr[c]     = *(const f16x8*)(bR + 32 * c);
        afr[8 + c] = *(const f16x8*)(bI + 32 * c);
    }
#pragma unroll
    for (int c = 0; c < 16; ++c) asm volatile("" : "+a"(afr[c]));

    if (tid < 256) {
        float xr = vre[b * 256 + tid], xi = vim[b * 256 + tid];
        v0h[0][tid]       = (f16)xr;
        v0h[0][256 + tid] = (f16)(-xi);
        v1h[0][tid]       = (f16)xi;
        v1h[0][256 + tid] = (f16)xr;
    }
    __syncthreads();

    const int niter = *pniter;
    const f16* vsel = (sel == 0) ? &v0h[0][0] : &v1h[0][0];

    float eig = 0.0f;

    auto npart = [&](int wb, const float4& y) {
        float s_ = 0.0f;
        if (sel < 2) s_ = y.x * y.x + y.y * y.y + y.z * y.z + y.w * y.w;
        s_ += __shfl_xor(s_, 1, 64);
        s_ += __shfl_xor(s_, 16, 64);
        s_ += __shfl_xor(s_, 32, 64);
        if (l == 0) part[wb][g] = s_;
    };
    auto vwrite = [&](int wb, const float4& y, float sc) {
        if (sel < 2) {
            uint32_t w0 = pack2(y.x * sc, y.y * sc);
            uint32_t w1 = pack2(y.z * sc, y.w * sc);
            int m0 = 16 * g + 4 * h;
            if (sel == 0) {
                *(uint2*)(void*)(&v0h[wb][m0])       = make_uint2(w0, w1);
                *(uint2*)(void*)(&v1h[wb][256 + m0]) = make_uint2(w0, w1);
            } else {
                *(uint2*)(void*)(&v1h[wb][m0])       = make_uint2(w0, w1);
                *(uint2*)(void*)(&v0h[wb][256 + m0]) =
                    make_uint2(w0 ^ 0x80008000u, w1 ^ 0x80008000u);
            }
        }
    };
    auto psum = [&](int rb) -> float {
        float4 q0 = *(const float4*)(&part[rb][0]);
        float4 q1 = *(const float4*)(&part[rb][4]);
        float4 q2 = *(const float4*)(&part[rb][8]);
        float4 q3 = *(const float4*)(&part[rb][12]);
        return (q0.x + q0.y + q0.z + q0.w) + (q1.x + q1.y + q1.z + q1.w)
             + (q2.x + q2.y + q2.z + q2.w) + (q3.x + q3.y + q3.z + q3.w);
    };

    float sc_m1 = 1.0f;   // s_{t-1}
    float nm2   = 1.0f;   // n_{t-2}

    // ---- peeled iteration 1 (synchronous): u_1 = y_1/e_1, n_1 = 1 ----
    if (niter >= 1) {
        float4 y = matvec(afr, vsel, h);
        npart(1, y);
        __syncthreads();
        float e1v = sqrtf(psum(1));
        float sc  = __builtin_amdgcn_rcpf(e1v + 1e-6f);
        vwrite(1, y, sc);
        eig = e1v;
        __syncthreads();
    }
    // ---- peeled iteration 2 (synchronous): u_2 = y_2/e_2, n_2 = 1 ----
    if (niter >= 2) {
        float4 y = matvec(afr, vsel + 512, h);
        npart(0, y);
        __syncthreads();
        float e2v = sqrtf(psum(0));
        float sc  = __builtin_amdgcn_rcpf(e2v + 1e-6f);
        vwrite(0, y, sc);
        eig = e2v;
        sc_m1 = sc;   // s_2
        nm2   = 1.0f; // n_1
        __syncthreads();
    }

    // ---- pipelined iterations 3..niter: one barrier each ----
    int wr = 0;
    for (int t = 3; t <= niter; ++t) {
        const int rd = wr;    // buffer holding u_{t-1}, part[rd] = q_{t-1}
        wr ^= 1;
        float q   = psum(rd);                                  // ||y_{t-1}||^2
        float e1v = __builtin_amdgcn_sqrtf(q);                 // e_{t-1}
        float nm1 = e1v * sc_m1;                               // n_{t-1}
        float sc  = nm2 * __builtin_amdgcn_rcpf(e1v * nm1 + 1e-12f);  // s_t
        float4 y  = matvec(afr, vsel + (size_t)rd * 512, h);   // y_t
        vwrite(wr, y, sc);
        npart(wr, y);
        nm2 = nm1; sc_m1 = sc;
        __syncthreads();
    }

    // ---- epilogue: exact eig = ||y_T|| / n_{T-1}
    if (niter >= 3) {
        float qT = psum(wr);
        eig = sqrtf(qT) / (nm2 + 1e-12f);
    }
    if (tid == 0) out[b] = eig;
}

extern "C" void kernel_launch(void* const* d_in, const int* in_sizes, int n_in,
                              void* d_out, int out_size, void* d_ws, size_t ws_size,
                              hipStream_t stream) {
    const float* Are = (const float*)d_in[0];
    const float* Aim = (const float*)d_in[1];
    const float* vre = (const float*)d_in[2];
    const float* vim = (const float*)d_in[3];
    const int* niter = (const int*)d_in[4];
    float* out = (float*)d_out;

    f16* At    = (f16*)d_ws;                                            // 64 MB
    f16* AhAre = (f16*)((char*)d_ws + (size_t)64 * 1024 * 1024);        // 32 MB
    f16* AhAim = (f16*)((char*)d_ws + (size_t)96 * 1024 * 1024);        // 32 MB

    k_transpose<<<dim3(8192), dim3(256), 0, stream>>>(Are, Aim, At);
    k_gemm<<<dim3(768), dim3(256), 0, stream>>>(At, AhAre, AhAim);
    k_power<<<dim3(256), dim3(1024), 0, stream>>>(AhAre, AhAim, vre, vim, niter, out);
}

// Round 5
// 140.528 us; speedup vs baseline: 1.1154x; 1.0244x over previous
//
#include <hip/hip_runtime.h>
#include <cstdint>

typedef _Float16 f16;
typedef _Float16 f16x2 __attribute__((ext_vector_type(2)));
typedef _Float16 f16x8 __attribute__((ext_vector_type(8)));
typedef float    f32x4 __attribute__((ext_vector_type(4)));

static __device__ __forceinline__ uint32_t pack2(float x, float y) {
    f16 hx = (f16)x, hy = (f16)y;
    uint32_t ux = __builtin_bit_cast(unsigned short, hx);
    uint32_t uy = __builtin_bit_cast(unsigned short, hy);
    return ux | (uy << 16);
}

// ---------------------------------------------------------------------------
// Kernel 1: A (f32, [B][M][N], re & im planes) -> At (f16, [plane][B][N][M])
// 64x64 tiles through LDS. grid = B*16*2, block = 256.  (HBM-roofline.)
// ---------------------------------------------------------------------------
__global__ __launch_bounds__(256) void k_transpose(const float* __restrict__ Are,
                                                   const float* __restrict__ Aim,
                                                   f16* __restrict__ At) {
    const int tid = threadIdx.x;
    int bid = blockIdx.x;
    const int plane = bid & 1; bid >>= 1;
    const int b = bid >> 4;
    const int tile = bid & 15;
    const int m0 = (tile >> 2) * 64, n0 = (tile & 3) * 64;

    const float* src = (plane ? Aim : Are) + (size_t)b * 65536;
    f16* dst = At + (size_t)plane * 16777216 + (size_t)b * 65536;

    __shared__ uint32_t lt[64][33];   // [n][m-pair], +1 pad

    const int rp = tid >> 3;          // row-pair 0..31  (m = m0 + 2*rp, +1)
    const int c0 = (tid & 7) * 8;     // col start (n offset)
    const float* s0 = src + (size_t)(m0 + rp * 2) * 256 + n0 + c0;
    float4 x0 = *(const float4*)(s0);
    float4 x1 = *(const float4*)(s0 + 4);
    float4 y0 = *(const float4*)(s0 + 256);
    float4 y1 = *(const float4*)(s0 + 260);

    lt[c0 + 0][rp] = pack2(x0.x, y0.x);
    lt[c0 + 1][rp] = pack2(x0.y, y0.y);
    lt[c0 + 2][rp] = pack2(x0.z, y0.z);
    lt[c0 + 3][rp] = pack2(x0.w, y0.w);
    lt[c0 + 4][rp] = pack2(x1.x, y1.x);
    lt[c0 + 5][rp] = pack2(x1.y, y1.y);
    lt[c0 + 6][rp] = pack2(x1.z, y1.z);
    lt[c0 + 7][rp] = pack2(x1.w, y1.w);

    __syncthreads();

    const int n = tid >> 2, mq = tid & 3;
    uint32_t u[8];
#pragma unroll
    for (int j = 0; j < 8; ++j) u[j] = lt[n][mq * 8 + j];
    f16* o = dst + (size_t)(n0 + n) * 256 + m0 + mq * 16;
    *(uint4*)(void*)(o)     = make_uint4(u[0], u[1], u[2], u[3]);
    *(uint4*)(void*)(o + 8) = make_uint4(u[4], u[5], u[6], u[7]);
}

// ---------------------------------------------------------------------------
// Kernel 2: AhA[b][n][c] = sum_m conj(A[m][n]) A[m][c].  MFMA 16x16x32 f16.
// HERMITIAN: only 3 quadrants computed (grid = B*3).  qq==1 mirrors its tile
// to quadrant (128-255, 0-127) via an LDS retranspose (Re copy, Im negate).
// XCD-aware block swizzle: the 3 blocks of a batch share one At slice.
// ---------------------------------------------------------------------------
__global__ __launch_bounds__(256, 2) void k_gemm(const f16* __restrict__ At,
                                                 f16* __restrict__ AhAre,
                                                 f16* __restrict__ AhAim) {
    const int tid = threadIdx.x;
    // bijective XCD swizzle for nwg=768 (768 % 8 == 0): chunk 96 per XCD
    int bid0 = blockIdx.x;
    int bid = (bid0 & 7) * 96 + (bid0 >> 3);
    const int b  = bid / 3;
    const int qq = bid - b * 3;                 // 0,1,2
    const int n0 = (qq == 2) ? 128 : 0;
    const int j0 = (qq >= 1) ? 128 : 0;

    const f16* Ar = At + (size_t)b * 65536;
    const f16* Ai = At + 16777216 + (size_t)b * 65536;

    __shared__ __align__(16) f16 ls[4][128 * 32];  // [Are_n, Aim_n, Are_j, Aim_j]

    const int l = tid & 63, w = tid >> 6;
    const int wr = w >> 1, wc = w & 1;
    const int lr = l & 15, lk = l >> 4;

    f32x4 aR[4][4], aI[4][4];
#pragma unroll
    for (int i = 0; i < 4; ++i)
#pragma unroll
        for (int j = 0; j < 4; ++j) { aR[i][j] = (f32x4)0.0f; aI[i][j] = (f32x4)0.0f; }

    for (int m0 = 0; m0 < 256; m0 += 32) {
        __syncthreads();
        // stage 4 tiles: [row(128)][k-slot(4) of 8 f16], XOR-swizzled slots
#pragma unroll
        for (int t = 0; t < 4; ++t) {
            const f16* src = (t & 1 ? Ai : Ar) + (size_t)(t < 2 ? n0 : j0) * 256 + m0;
#pragma unroll
            for (int cc = 0; cc < 2; ++cc) {
                int chunk = tid * 2 + cc;              // 0..511
                int r = chunk >> 2, s = chunk & 3;
                int klog = s ^ ((r >> 1) & 3);
                uint4 g = *(const uint4*)(src + (size_t)r * 256 + klog * 8);
                *(uint4*)(&ls[t][r * 32 + s * 8]) = g;
            }
        }
        __syncthreads();

        f16x8 bre[4], bim[4];
#pragma unroll
        for (int j = 0; j < 4; ++j) {
            int rloc = wc * 64 + j * 16 + lr;
            int s1 = lk ^ ((rloc >> 1) & 3);
            bre[j] = *(const f16x8*)(&ls[2][rloc * 32 + s1 * 8]);
            bim[j] = *(const f16x8*)(&ls[3][rloc * 32 + s1 * 8]);
        }
#pragma unroll
        for (int i = 0; i < 4; ++i) {
            int rloc = wr * 64 + i * 16 + lr;
            int s1 = lk ^ ((rloc >> 1) & 3);
            f16x8 are = *(const f16x8*)(&ls[0][rloc * 32 + s1 * 8]);
            uint4 un  = *(const uint4*)(&ls[1][rloc * 32 + s1 * 8]);
            f16x8 aim = __builtin_bit_cast(f16x8, un);
            uint4 nn = make_uint4(un.x ^ 0x80008000u, un.y ^ 0x80008000u,
                                  un.z ^ 0x80008000u, un.w ^ 0x80008000u);
            f16x8 nai = __builtin_bit_cast(f16x8, nn);
#pragma unroll
            for (int j = 0; j < 4; ++j) {
                aR[i][j] = __builtin_amdgcn_mfma_f32_16x16x32_f16(are, bre[j], aR[i][j], 0, 0, 0);
                aR[i][j] = __builtin_amdgcn_mfma_f32_16x16x32_f16(aim, bim[j], aR[i][j], 0, 0, 0);
                aI[i][j] = __builtin_amdgcn_mfma_f32_16x16x32_f16(are, bim[j], aI[i][j], 0, 0, 0);
                aI[i][j] = __builtin_amdgcn_mfma_f32_16x16x32_f16(nai, bre[j], aI[i][j], 0, 0, 0);
            }
        }
    }

    f16* oR = AhAre + (size_t)b * 65536;
    f16* oI = AhAim + (size_t)b * 65536;
#pragma unroll
    for (int i = 0; i < 4; ++i)
#pragma unroll
        for (int j = 0; j < 4; ++j)
#pragma unroll
            for (int r = 0; r < 4; ++r) {
                int n = n0 + wr * 64 + i * 16 + lk * 4 + r;
                int c = j0 + wc * 64 + j * 16 + lr;
                oR[(size_t)n * 256 + c] = (f16)aR[i][j][r];
                oI[(size_t)n * 256 + c] = (f16)aI[i][j][r];
            }

    // ---- Hermitian mirror: quadrant (128+jj, nn) = conj(our (nn, 128+jj)) ----
    // Each thread copies 64 f16 of its row-half as 8 x uint4 (uint4 = 8 f16!).
    if (qq == 1) {
        f16* lsm = &ls[0][0];                      // reuse 32 KB as [128][128]
        const int jj_out = tid >> 1, hf = (tid & 1) * 64;

        // Re plane: copy
        __syncthreads();
#pragma unroll
        for (int i = 0; i < 4; ++i)
#pragma unroll
            for (int j = 0; j < 4; ++j)
#pragma unroll
                for (int r = 0; r < 4; ++r) {
                    int nn = wr * 64 + i * 16 + lk * 4 + r;
                    int jj = wc * 64 + j * 16 + lr;
                    lsm[jj * 128 + nn] = (f16)aR[i][j][r];
                }
        __syncthreads();
        {
            const f16* srow = lsm + jj_out * 128 + hf;
            f16* drow = oR + (size_t)(128 + jj_out) * 256 + hf;
#pragma unroll
            for (int ch = 0; ch < 8; ++ch)
                *(uint4*)(void*)(drow + ch * 8) = *(const uint4*)(srow + ch * 8);
        }
        __syncthreads();

        // Im plane: negate
#pragma unroll
        for (int i = 0; i < 4; ++i)
#pragma unroll
            for (int j = 0; j < 4; ++j)
#pragma unroll
                for (int r = 0; r < 4; ++r) {
                    int nn = wr * 64 + i * 16 + lk * 4 + r;
                    int jj = wc * 64 + j * 16 + lr;
                    lsm[jj * 128 + nn] = (f16)(-aI[i][j][r]);
                }
        __syncthreads();
        {
            const f16* srow = lsm + jj_out * 128 + hf;
            f16* drow = oI + (size_t)(128 + jj_out) * 256 + hf;
#pragma unroll
            for (int ch = 0; ch < 8; ++ch)
                *(uint4*)(void*)(drow + ch * 8) = *(const uint4*)(srow + ch * 8);
        }
    }
}

// ---------------------------------------------------------------------------
// Kernel 3: power iteration, 4-WAVE / 64-ROWS-PER-WAVE form.
// Rationale (rocprof r4): old 16-wave form issued 256 ds_read_b128 per
// block-iteration (16 waves x 16) -- LDS-instruction-throughput-bound
// (~12-16 cyc each ~= 4100 cyc/iter ~= measured 2.1us/iter).  The B-operand
// (v-chunk) is IDENTICAL for every 16-row group, so each wave now owns 4
// row-groups (64 rows): one ds_read_b128 feeds 4 MFMA -> 64 reads/block-iter
// (4x cut in the saturated pipe).  afr = 4x16 f16x8 = 256 AGPR; ~400 total
// regs -> 1 wave/SIMD, block = 4 waves (launch_bounds(256,1)).
// MFMA count and per-row accumulation order are bitwise-identical to the
// 16-wave version.  Deferred normalization (stable form) retained.
// ---------------------------------------------------------------------------
static __device__ __forceinline__ void matvec4(const f16x8 (&afr)[4][16],
                                               const f16* __restrict__ vs, int h,
                                               float4 (&y)[4]) {
    f32x4 P0[4], P1[4];
#pragma unroll
    for (int rg = 0; rg < 4; ++rg) { P0[rg] = (f32x4)0.0f; P1[rg] = (f32x4)0.0f; }
#pragma unroll
    for (int c = 0; c < 16; ++c) {
        f16x8 bf = *(const f16x8*)(vs + 32 * c + 8 * h);
#pragma unroll
        for (int rg = 0; rg < 4; ++rg) {
            if (c & 1) P1[rg] = __builtin_amdgcn_mfma_f32_16x16x32_f16(afr[rg][c], bf, P1[rg], 0, 0, 0);
            else       P0[rg] = __builtin_amdgcn_mfma_f32_16x16x32_f16(afr[rg][c], bf, P0[rg], 0, 0, 0);
        }
    }
#pragma unroll
    for (int rg = 0; rg < 4; ++rg)
        y[rg] = make_float4(P0[rg][0] + P1[rg][0], P0[rg][1] + P1[rg][1],
                            P0[rg][2] + P1[rg][2], P0[rg][3] + P1[rg][3]);
}

__global__ __launch_bounds__(256, 1) void k_power(const f16* __restrict__ AhAre,
                                                  const f16* __restrict__ AhAim,
                                                  const float* __restrict__ vre,
                                                  const float* __restrict__ vim,
                                                  const int* __restrict__ pniter,
                                                  float* __restrict__ out) {
    const int tid = threadIdx.x;
    const int b = blockIdx.x;
    const int l = tid & 63;            // lane
    const int g = tid >> 6;            // wave 0..3
    const int sel = l & 15;            // A-row-within-group / B-col
    const int h = l >> 4;              // k-slot 0..3

    __shared__ __align__(16) f16 v0h[2][512];   // [buf][ vr ; -vi ]
    __shared__ __align__(16) f16 v1h[2][512];   // [buf][ vi ;  vr ]
    __shared__ __align__(16) float part[2][4];

    // ---- load A fragments: wave g owns rows 64g .. 64g+63 (4 row-groups)
    f16x8 afr[4][16];
#pragma unroll
    for (int rg = 0; rg < 4; ++rg) {
        const int m = 64 * g + 16 * rg + sel;
        const f16* bR = AhAre + (size_t)b * 65536 + (size_t)m * 256 + 8 * h;
        const f16* bI = AhAim + (size_t)b * 65536 + (size_t)m * 256 + 8 * h;
#pragma unroll
        for (int c = 0; c < 8; ++c) {
            afr[rg][c]     = *(const f16x8*)(bR + 32 * c);
            afr[rg][8 + c] = *(const f16x8*)(bI + 32 * c);
        }
    }
#pragma unroll
    for (int rg = 0; rg < 4; ++rg)
#pragma unroll
        for (int c = 0; c < 16; ++c) asm volatile("" : "+a"(afr[rg][c]));

    {
        float xr = vre[b * 256 + tid], xi = vim[b * 256 + tid];
        v0h[0][tid]       = (f16)xr;
        v0h[0][256 + tid] = (f16)(-xi);
        v1h[0][tid]       = (f16)xi;
        v1h[0][256 + tid] = (f16)xr;
    }
    __syncthreads();

    const int niter = *pniter;
    const f16* vsel = (sel == 0) ? &v0h[0][0] : &v1h[0][0];

    float eig = 0.0f;

    auto npart = [&](int wb, const float4 (&y)[4]) {
        float s_ = 0.0f;
        if (sel < 2) {
#pragma unroll
            for (int rg = 0; rg < 4; ++rg)
                s_ += y[rg].x * y[rg].x + y[rg].y * y[rg].y
                    + y[rg].z * y[rg].z + y[rg].w * y[rg].w;
        }
        s_ += __shfl_xor(s_, 1, 64);
        s_ += __shfl_xor(s_, 16, 64);
        s_ += __shfl_xor(s_, 32, 64);
        if (l == 0) part[wb][g] = s_;
    };
    auto vwrite = [&](int wb, const float4 (&y)[4], float sc) {
        if (sel < 2) {
#pragma unroll
            for (int rg = 0; rg < 4; ++rg) {
                uint32_t w0 = pack2(y[rg].x * sc, y[rg].y * sc);
                uint32_t w1 = pack2(y[rg].z * sc, y[rg].w * sc);
                int m0 = 64 * g + 16 * rg + 4 * h;    // 4 consecutive rows
                if (sel == 0) {                       // y = new vr
                    *(uint2*)(void*)(&v0h[wb][m0])       = make_uint2(w0, w1);
                    *(uint2*)(void*)(&v1h[wb][256 + m0]) = make_uint2(w0, w1);
                } else {                              // y = new vi
                    *(uint2*)(void*)(&v1h[wb][m0])       = make_uint2(w0, w1);
                    *(uint2*)(void*)(&v0h[wb][256 + m0]) =
                        make_uint2(w0 ^ 0x80008000u, w1 ^ 0x80008000u);
                }
            }
        }
    };
    auto psum = [&](int rb) -> float {
        float4 q = *(const float4*)(&part[rb][0]);
        return (q.x + q.y) + (q.z + q.w);
    };

    float sc_m1 = 1.0f;   // s_{t-1}
    float nm2   = 1.0f;   // n_{t-2}

    float4 y[4];

    // ---- peeled iteration 1 (synchronous): u_1 = y_1/e_1, n_1 = 1 ----
    if (niter >= 1) {
        matvec4(afr, vsel, h, y);
        npart(1, y);
        __syncthreads();
        float e1v = sqrtf(psum(1));
        float sc  = __builtin_amdgcn_rcpf(e1v + 1e-6f);
        vwrite(1, y, sc);
        eig = e1v;
        __syncthreads();
    }
    // ---- peeled iteration 2 (synchronous): u_2 = y_2/e_2, n_2 = 1 ----
    if (niter >= 2) {
        matvec4(afr, vsel + 512, h, y);
        npart(0, y);
        __syncthreads();
        float e2v = sqrtf(psum(0));
        float sc  = __builtin_amdgcn_rcpf(e2v + 1e-6f);
        vwrite(0, y, sc);
        eig = e2v;
        sc_m1 = sc;   // s_2
        nm2   = 1.0f; // n_1
        __syncthreads();
    }

    // ---- pipelined iterations 3..niter: one barrier each ----
    int wr = 0;
    for (int t = 3; t <= niter; ++t) {
        const int rd = wr;    // buffer holding u_{t-1}, part[rd] = q_{t-1}
        wr ^= 1;
        float q   = psum(rd);                                  // ||y_{t-1}||^2
        float e1v = __builtin_amdgcn_sqrtf(q);                 // e_{t-1}
        float nm1 = e1v * sc_m1;                               // n_{t-1}
        float sc  = nm2 * __builtin_amdgcn_rcpf(e1v * nm1 + 1e-12f);  // s_t
        matvec4(afr, vsel + (size_t)rd * 512, h, y);           // y_t
        vwrite(wr, y, sc);
        npart(wr, y);
        nm2 = nm1; sc_m1 = sc;
        __syncthreads();
    }

    // ---- epilogue: exact eig = ||y_T|| / n_{T-1}
    if (niter >= 3) {
        float qT = psum(wr);
        eig = sqrtf(qT) / (nm2 + 1e-12f);
    }
    if (tid == 0) out[b] = eig;
}

extern "C" void kernel_launch(void* const* d_in, const int* in_sizes, int n_in,
                              void* d_out, int out_size, void* d_ws, size_t ws_size,
                              hipStream_t stream) {
    const float* Are = (const float*)d_in[0];
    const float* Aim = (const float*)d_in[1];
    const float* vre = (const float*)d_in[2];
    const float* vim = (const float*)d_in[3];
    const int* niter = (const int*)d_in[4];
    float* out = (float*)d_out;

    f16* At    = (f16*)d_ws;                                            // 64 MB
    f16* AhAre = (f16*)((char*)d_ws + (size_t)64 * 1024 * 1024);        // 32 MB
    f16* AhAim = (f16*)((char*)d_ws + (size_t)96 * 1024 * 1024);        // 32 MB

    k_transpose<<<dim3(8192), dim3(256), 0, stream>>>(Are, Aim, At);
    k_gemm<<<dim3(768), dim3(256), 0, stream>>>(At, AhAre, AhAim);
    k_power<<<dim3(256), dim3(256), 0, stream>>>(AhAre, AhAim, vre, vim, niter, out);
}

// Round 6
// 122.703 us; speedup vs baseline: 1.2774x; 1.1453x over previous
//
#include <hip/hip_runtime.h>
#include <cstdint>

typedef _Float16 f16;
typedef _Float16 f16x2 __attribute__((ext_vector_type(2)));
typedef _Float16 f16x8 __attribute__((ext_vector_type(8)));
typedef float    f32x4 __attribute__((ext_vector_type(4)));

static __device__ __forceinline__ uint32_t pack2(float x, float y) {
    f16 hx = (f16)x, hy = (f16)y;
    uint32_t ux = __builtin_bit_cast(unsigned short, hx);
    uint32_t uy = __builtin_bit_cast(unsigned short, hy);
    return ux | (uy << 16);
}

// ---------------------------------------------------------------------------
// Kernel 1 (FUSED transpose+gemm): AhA[b][n][c] = sum_m conj(A[m][n]) A[m][c]
// directly from f32 A planes.  Staging reads A rows coalesced (float4),
// packs m-pairs to f16x2, and writes the SAME swizzled ls layout the MFMA
// loop always used (ls[t][r*32 + s*8 + e] = A[m0+klog*8+e][p0+r],
// klog = s ^ ((r>>1)&3)).  Removes the 60us k_transpose + 64MB At bounce.
// HERMITIAN: 3 quadrants (grid = B*3), qq==1 mirrors via LDS retranspose.
// XCD-aware swizzle: 3 blocks of a batch share one A slice in L2.
// ---------------------------------------------------------------------------
__global__ __launch_bounds__(256, 2) void k_gemm(const float* __restrict__ Are,
                                                 const float* __restrict__ Aim,
                                                 f16* __restrict__ AhAre,
                                                 f16* __restrict__ AhAim) {
    const int tid = threadIdx.x;
    // bijective XCD swizzle for nwg=768 (768 % 8 == 0): chunk 96 per XCD
    int bid0 = blockIdx.x;
    int bid = (bid0 & 7) * 96 + (bid0 >> 3);
    const int b  = bid / 3;
    const int qq = bid - b * 3;                 // 0,1,2
    const int n0 = (qq == 2) ? 128 : 0;
    const int j0 = (qq >= 1) ? 128 : 0;

    __shared__ __align__(16) f16 ls[4][128 * 32];  // [Are_n, Aim_n, Are_j, Aim_j]

    const int l = tid & 63, w = tid >> 6;
    const int wr = w >> 1, wc = w & 1;
    const int lr = l & 15, lk = l >> 4;

    // staging decomposition: u = m-pair 0..15, fp = col-group of 8
    const int u = tid & 15;
    const int fp = tid >> 4;
    const int su = (u >> 2);        // slot base for this m-pair
    const int uq = (u & 3);         // u32 slot position

    f32x4 aR[4][4], aI[4][4];
#pragma unroll
    for (int i = 0; i < 4; ++i)
#pragma unroll
        for (int j = 0; j < 4; ++j) { aR[i][j] = (f32x4)0.0f; aI[i][j] = (f32x4)0.0f; }

    for (int m0 = 0; m0 < 256; m0 += 32) {
        __syncthreads();
        // fused stage: 4 tiles of 32m x 128n f32 -> f16, transposed in LDS
#pragma unroll
        for (int t = 0; t < 4; ++t) {
            const float* sp = (t & 1 ? Aim : Are) + (size_t)b * 65536
                            + (size_t)(m0 + 2 * u) * 256 + (t < 2 ? n0 : j0) + fp * 8;
            float4 x0 = *(const float4*)(sp);
            float4 x1 = *(const float4*)(sp + 4);
            float4 y0 = *(const float4*)(sp + 256);
            float4 y1 = *(const float4*)(sp + 260);
            float xv[8] = {x0.x, x0.y, x0.z, x0.w, x1.x, x1.y, x1.z, x1.w};
            float yv[8] = {y0.x, y0.y, y0.z, y0.w, y1.x, y1.y, y1.z, y1.w};
            uint32_t* lw = (uint32_t*)&ls[t][0];
#pragma unroll
            for (int i = 0; i < 8; ++i) {
                int r = fp * 8 + i;
                int s = su ^ ((r >> 1) & 3);
                lw[r * 16 + s * 4 + uq] = pack2(xv[i], yv[i]);
            }
        }
        __syncthreads();

        f16x8 bre[4], bim[4];
#pragma unroll
        for (int j = 0; j < 4; ++j) {
            int rloc = wc * 64 + j * 16 + lr;
            int s1 = lk ^ ((rloc >> 1) & 3);
            bre[j] = *(const f16x8*)(&ls[2][rloc * 32 + s1 * 8]);
            bim[j] = *(const f16x8*)(&ls[3][rloc * 32 + s1 * 8]);
        }
#pragma unroll
        for (int i = 0; i < 4; ++i) {
            int rloc = wr * 64 + i * 16 + lr;
            int s1 = lk ^ ((rloc >> 1) & 3);
            f16x8 are = *(const f16x8*)(&ls[0][rloc * 32 + s1 * 8]);
            uint4 un  = *(const uint4*)(&ls[1][rloc * 32 + s1 * 8]);
            f16x8 aim = __builtin_bit_cast(f16x8, un);
            uint4 nn = make_uint4(un.x ^ 0x80008000u, un.y ^ 0x80008000u,
                                  un.z ^ 0x80008000u, un.w ^ 0x80008000u);
            f16x8 nai = __builtin_bit_cast(f16x8, nn);
#pragma unroll
            for (int j = 0; j < 4; ++j) {
                aR[i][j] = __builtin_amdgcn_mfma_f32_16x16x32_f16(are, bre[j], aR[i][j], 0, 0, 0);
                aR[i][j] = __builtin_amdgcn_mfma_f32_16x16x32_f16(aim, bim[j], aR[i][j], 0, 0, 0);
                aI[i][j] = __builtin_amdgcn_mfma_f32_16x16x32_f16(are, bim[j], aI[i][j], 0, 0, 0);
                aI[i][j] = __builtin_amdgcn_mfma_f32_16x16x32_f16(nai, bre[j], aI[i][j], 0, 0, 0);
            }
        }
    }

    f16* oR = AhAre + (size_t)b * 65536;
    f16* oI = AhAim + (size_t)b * 65536;
#pragma unroll
    for (int i = 0; i < 4; ++i)
#pragma unroll
        for (int j = 0; j < 4; ++j)
#pragma unroll
            for (int r = 0; r < 4; ++r) {
                int n = n0 + wr * 64 + i * 16 + lk * 4 + r;
                int c = j0 + wc * 64 + j * 16 + lr;
                oR[(size_t)n * 256 + c] = (f16)aR[i][j][r];
                oI[(size_t)n * 256 + c] = (f16)aI[i][j][r];
            }

    // ---- Hermitian mirror: quadrant (128+jj, nn) = conj(our (nn, 128+jj)) ----
    // Each thread copies 64 f16 of its row-half as 8 x uint4 (uint4 = 8 f16!).
    if (qq == 1) {
        f16* lsm = &ls[0][0];                      // reuse 32 KB as [128][128]
        const int jj_out = tid >> 1, hf = (tid & 1) * 64;

        // Re plane: copy
        __syncthreads();
#pragma unroll
        for (int i = 0; i < 4; ++i)
#pragma unroll
            for (int j = 0; j < 4; ++j)
#pragma unroll
                for (int r = 0; r < 4; ++r) {
                    int nn = wr * 64 + i * 16 + lk * 4 + r;
                    int jj = wc * 64 + j * 16 + lr;
                    lsm[jj * 128 + nn] = (f16)aR[i][j][r];
                }
        __syncthreads();
        {
            const f16* srow = lsm + jj_out * 128 + hf;
            f16* drow = oR + (size_t)(128 + jj_out) * 256 + hf;
#pragma unroll
            for (int ch = 0; ch < 8; ++ch)
                *(uint4*)(void*)(drow + ch * 8) = *(const uint4*)(srow + ch * 8);
        }
        __syncthreads();

        // Im plane: negate
#pragma unroll
        for (int i = 0; i < 4; ++i)
#pragma unroll
            for (int j = 0; j < 4; ++j)
#pragma unroll
                for (int r = 0; r < 4; ++r) {
                    int nn = wr * 64 + i * 16 + lk * 4 + r;
                    int jj = wc * 64 + j * 16 + lr;
                    lsm[jj * 128 + nn] = (f16)(-aI[i][j][r]);
                }
        __syncthreads();
        {
            const f16* srow = lsm + jj_out * 128 + hf;
            f16* drow = oI + (size_t)(128 + jj_out) * 256 + hf;
#pragma unroll
            for (int ch = 0; ch < 8; ++ch)
                *(uint4*)(void*)(drow + ch * 8) = *(const uint4*)(srow + ch * 8);
        }
    }
}

// ---------------------------------------------------------------------------
// Kernel 2: power iteration, 8-WAVE / 32-ROWS-PER-WAVE form.
// r5 lesson: 4-wave/64-row cut LDS instrs 4x but time only -8% -- the
// bottleneck is LATENCY EXPOSURE at 1 wave/SIMD, and at 436/512 regs the
// scheduler serializes the v-fragment loads.  This version: 8 waves
// (2/SIMD TLP, launch_bounds(512,2) caps regs at 256: 128 AGPR afr +
// ~120 VGPR), rg=2 row-groups/wave, and bf[16] loaded in a SEPARATE
// batched loop (16 outstanding ds_reads) before the MFMA sweep.
// Deferred normalization (stable form) retained.
// ---------------------------------------------------------------------------
static __device__ __forceinline__ void matvec2(const f16x8 (&afr)[2][16],
                                               const f16* __restrict__ vs, int h,
                                               float4 (&y)[2]) {
    f16x8 bf[16];
#pragma unroll
    for (int c = 0; c < 16; ++c) bf[c] = *(const f16x8*)(vs + 32 * c + 8 * h);
    f32x4 P0[2], P1[2];
#pragma unroll
    for (int rg = 0; rg < 2; ++rg) { P0[rg] = (f32x4)0.0f; P1[rg] = (f32x4)0.0f; }
#pragma unroll
    for (int c = 0; c < 16; ++c) {
#pragma unroll
        for (int rg = 0; rg < 2; ++rg) {
            if (c & 1) P1[rg] = __builtin_amdgcn_mfma_f32_16x16x32_f16(afr[rg][c], bf[c], P1[rg], 0, 0, 0);
            else       P0[rg] = __builtin_amdgcn_mfma_f32_16x16x32_f16(afr[rg][c], bf[c], P0[rg], 0, 0, 0);
        }
    }
#pragma unroll
    for (int rg = 0; rg < 2; ++rg)
        y[rg] = make_float4(P0[rg][0] + P1[rg][0], P0[rg][1] + P1[rg][1],
                            P0[rg][2] + P1[rg][2], P0[rg][3] + P1[rg][3]);
}

__global__ __launch_bounds__(512, 2) void k_power(const f16* __restrict__ AhAre,
                                                  const f16* __restrict__ AhAim,
                                                  const float* __restrict__ vre,
                                                  const float* __restrict__ vim,
                                                  const int* __restrict__ pniter,
                                                  float* __restrict__ out) {
    const int tid = threadIdx.x;
    const int b = blockIdx.x;
    const int l = tid & 63;            // lane
    const int g = tid >> 6;            // wave 0..7
    const int sel = l & 15;            // A-row-within-group / B-col
    const int h = l >> 4;              // k-slot 0..3

    __shared__ __align__(16) f16 v0h[2][512];   // [buf][ vr ; -vi ]
    __shared__ __align__(16) f16 v1h[2][512];   // [buf][ vi ;  vr ]
    __shared__ __align__(16) float part[2][8];

    // ---- load A fragments: wave g owns rows 32g .. 32g+31 (2 row-groups)
    f16x8 afr[2][16];
#pragma unroll
    for (int rg = 0; rg < 2; ++rg) {
        const int m = 32 * g + 16 * rg + sel;
        const f16* bR = AhAre + (size_t)b * 65536 + (size_t)m * 256 + 8 * h;
        const f16* bI = AhAim + (size_t)b * 65536 + (size_t)m * 256 + 8 * h;
#pragma unroll
        for (int c = 0; c < 8; ++c) {
            afr[rg][c]     = *(const f16x8*)(bR + 32 * c);
            afr[rg][8 + c] = *(const f16x8*)(bI + 32 * c);
        }
    }
#pragma unroll
    for (int rg = 0; rg < 2; ++rg)
#pragma unroll
        for (int c = 0; c < 16; ++c) asm volatile("" : "+a"(afr[rg][c]));

    if (tid < 256) {
        float xr = vre[b * 256 + tid], xi = vim[b * 256 + tid];
        v0h[0][tid]       = (f16)xr;
        v0h[0][256 + tid] = (f16)(-xi);
        v1h[0][tid]       = (f16)xi;
        v1h[0][256 + tid] = (f16)xr;
    }
    __syncthreads();

    const int niter = *pniter;
    const f16* vsel = (sel == 0) ? &v0h[0][0] : &v1h[0][0];

    float eig = 0.0f;

    auto npart = [&](int wb, const float4 (&y)[2]) {
        float s_ = 0.0f;
        if (sel < 2) {
#pragma unroll
            for (int rg = 0; rg < 2; ++rg)
                s_ += y[rg].x * y[rg].x + y[rg].y * y[rg].y
                    + y[rg].z * y[rg].z + y[rg].w * y[rg].w;
        }
        s_ += __shfl_xor(s_, 1, 64);
        s_ += __shfl_xor(s_, 16, 64);
        s_ += __shfl_xor(s_, 32, 64);
        if (l == 0) part[wb][g] = s_;
    };
    auto vwrite = [&](int wb, const float4 (&y)[2], float sc) {
        if (sel < 2) {
#pragma unroll
            for (int rg = 0; rg < 2; ++rg) {
                uint32_t w0 = pack2(y[rg].x * sc, y[rg].y * sc);
                uint32_t w1 = pack2(y[rg].z * sc, y[rg].w * sc);
                int m0 = 32 * g + 16 * rg + 4 * h;    // 4 consecutive rows
                if (sel == 0) {                       // y = new vr
                    *(uint2*)(void*)(&v0h[wb][m0])       = make_uint2(w0, w1);
                    *(uint2*)(void*)(&v1h[wb][256 + m0]) = make_uint2(w0, w1);
                } else {                              // y = new vi
                    *(uint2*)(void*)(&v1h[wb][m0])       = make_uint2(w0, w1);
                    *(uint2*)(void*)(&v0h[wb][256 + m0]) =
                        make_uint2(w0 ^ 0x80008000u, w1 ^ 0x80008000u);
                }
            }
        }
    };
    auto psum = [&](int rb) -> float {
        float4 q0 = *(const float4*)(&part[rb][0]);
        float4 q1 = *(const float4*)(&part[rb][4]);
        return (q0.x + q0.y + q0.z + q0.w) + (q1.x + q1.y + q1.z + q1.w);
    };

    float sc_m1 = 1.0f;   // s_{t-1}
    float nm2   = 1.0f;   // n_{t-2}

    float4 y[2];

    // ---- peeled iteration 1 (synchronous): u_1 = y_1/e_1, n_1 = 1 ----
    if (niter >= 1) {
        matvec2(afr, vsel, h, y);
        npart(1, y);
        __syncthreads();
        float e1v = sqrtf(psum(1));
        float sc  = __builtin_amdgcn_rcpf(e1v + 1e-6f);
        vwrite(1, y, sc);
        eig = e1v;
        __syncthreads();
    }
    // ---- peeled iteration 2 (synchronous): u_2 = y_2/e_2, n_2 = 1 ----
    if (niter >= 2) {
        matvec2(afr, vsel + 512, h, y);
        npart(0, y);
        __syncthreads();
        float e2v = sqrtf(psum(0));
        float sc  = __builtin_amdgcn_rcpf(e2v + 1e-6f);
        vwrite(0, y, sc);
        eig = e2v;
        sc_m1 = sc;   // s_2
        nm2   = 1.0f; // n_1
        __syncthreads();
    }

    // ---- pipelined iterations 3..niter: one barrier each ----
    int wr = 0;
    for (int t = 3; t <= niter; ++t) {
        const int rd = wr;    // buffer holding u_{t-1}, part[rd] = q_{t-1}
        wr ^= 1;
        float q   = psum(rd);                                  // ||y_{t-1}||^2
        float e1v = __builtin_amdgcn_sqrtf(q);                 // e_{t-1}
        float nm1 = e1v * sc_m1;                               // n_{t-1}
        float sc  = nm2 * __builtin_amdgcn_rcpf(e1v * nm1 + 1e-12f);  // s_t
        matvec2(afr, vsel + (size_t)rd * 512, h, y);           // y_t
        vwrite(wr, y, sc);
        npart(wr, y);
        nm2 = nm1; sc_m1 = sc;
        __syncthreads();
    }

    // ---- epilogue: exact eig = ||y_T|| / n_{T-1}
    if (niter >= 3) {
        float qT = psum(wr);
        eig = sqrtf(qT) / (nm2 + 1e-12f);
    }
    if (tid == 0) out[b] = eig;
}

extern "C" void kernel_launch(void* const* d_in, const int* in_sizes, int n_in,
                              void* d_out, int out_size, void* d_ws, size_t ws_size,
                              hipStream_t stream) {
    const float* Are = (const float*)d_in[0];
    const float* Aim = (const float*)d_in[1];
    const float* vre = (const float*)d_in[2];
    const float* vim = (const float*)d_in[3];
    const int* niter = (const int*)d_in[4];
    float* out = (float*)d_out;

    f16* AhAre = (f16*)d_ws;                                            // 32 MB
    f16* AhAim = (f16*)((char*)d_ws + (size_t)32 * 1024 * 1024);        // 32 MB

    k_gemm<<<dim3(768), dim3(256), 0, stream>>>(Are, Aim, AhAre, AhAim);
    k_power<<<dim3(256), dim3(512), 0, stream>>>(AhAre, AhAim, vre, vim, niter, out);
}

// Round 7
// 97.592 us; speedup vs baseline: 1.6061x; 1.2573x over previous
//
#include <hip/hip_runtime.h>
#include <cstdint>

typedef _Float16 f16;
typedef _Float16 f16x2 __attribute__((ext_vector_type(2)));
typedef _Float16 f16x8 __attribute__((ext_vector_type(8)));
typedef float    f32x4 __attribute__((ext_vector_type(4)));

static __device__ __forceinline__ uint32_t pack2(float x, float y) {
    f16 hx = (f16)x, hy = (f16)y;
    uint32_t ux = __builtin_bit_cast(unsigned short, hx);
    uint32_t uy = __builtin_bit_cast(unsigned short, hy);
    return ux | (uy << 16);
}

// ---------------------------------------------------------------------------
// Kernel 1 (fused transpose+gemm, ONE BLOCK PER BATCH):
//   AhA[b][n][c] = sum_m conj(A[m][n]) A[m][c]   from f32 A planes.
// grid = 256 (1 block/CU), block = 512 (8 waves).  Per K-step the block
// stages the FULL 256-row A slice (Re+Im, 32KB LDS) -- every A byte is
// fetched from HBM exactly once (r6's 3-blocks/batch read it 2-3x and ran
// at 1.4TB/s achieved).  A- and B-fragments both read from the same two
// full-width tiles.  Wave g owns out rows 16g (all 256 cols, 16 tiles) +
// rows 128+16g cols 128.. (8 tiles) = 24 tiles = 192 acc regs; lower-left
// quadrant is the Hermitian mirror of q1 (LDS retranspose, Re copy/Im neg).
// Staging map + swizzle identical to the verified r6 formulas (fp now 0..31).
// ---------------------------------------------------------------------------
__global__ __launch_bounds__(512, 2) void k_gemm(const float* __restrict__ Are,
                                                 const float* __restrict__ Aim,
                                                 f16* __restrict__ AhAre,
                                                 f16* __restrict__ AhAim) {
    const int tid = threadIdx.x;
    const int b = blockIdx.x;

    __shared__ __align__(16) f16 ls[2][256 * 32];   // [Re, Im]: 256 rows x 32 k

    const int l = tid & 63, g = tid >> 6;      // lane, wave 0..7
    const int lr = l & 15, lk = l >> 4;

    // staging decomposition: u = m-pair 0..15, fp = row-group of 8 (0..31)
    const int u = tid & 15;
    const int fp = tid >> 4;
    const int su = u >> 2, uq = u & 3;

    f32x4 cR[16], cI[16], dR[8], dI[8];
#pragma unroll
    for (int j = 0; j < 16; ++j) { cR[j] = (f32x4)0.0f; cI[j] = (f32x4)0.0f; }
#pragma unroll
    for (int j = 0; j < 8; ++j)  { dR[j] = (f32x4)0.0f; dI[j] = (f32x4)0.0f; }

    for (int m0 = 0; m0 < 256; m0 += 32) {
        __syncthreads();
        // stage both planes: 256 rows x 32 m, f32 -> f16 pack, swizzled slots.
        // all 8 float4 loads issued before any pack (batched outstanding).
        float4 v[2][4];
#pragma unroll
        for (int t = 0; t < 2; ++t) {
            const float* sp = (t ? Aim : Are) + (size_t)b * 65536
                            + (size_t)(m0 + 2 * u) * 256 + fp * 8;
            v[t][0] = *(const float4*)(sp);
            v[t][1] = *(const float4*)(sp + 4);
            v[t][2] = *(const float4*)(sp + 256);
            v[t][3] = *(const float4*)(sp + 260);
        }
#pragma unroll
        for (int t = 0; t < 2; ++t) {
            float xv[8] = {v[t][0].x, v[t][0].y, v[t][0].z, v[t][0].w,
                           v[t][1].x, v[t][1].y, v[t][1].z, v[t][1].w};
            float yv[8] = {v[t][2].x, v[t][2].y, v[t][2].z, v[t][2].w,
                           v[t][3].x, v[t][3].y, v[t][3].z, v[t][3].w};
            uint32_t* lw = (uint32_t*)&ls[t][0];
#pragma unroll
            for (int i = 0; i < 8; ++i) {
                int r = fp * 8 + i;
                int s = su ^ ((r >> 1) & 3);
                lw[r * 16 + s * 4 + uq] = pack2(xv[i], yv[i]);
            }
        }
        __syncthreads();

        // A fragments for this wave's two row-blocks
        const int r1 = 16 * g + lr;
        const int r2 = 128 + 16 * g + lr;
        const int s1 = lk ^ ((r1 >> 1) & 3);
        const int s2 = lk ^ ((r2 >> 1) & 3);
        f16x8 a1re = *(const f16x8*)(&ls[0][r1 * 32 + s1 * 8]);
        uint4 u1   = *(const uint4*)(&ls[1][r1 * 32 + s1 * 8]);
        f16x8 a2re = *(const f16x8*)(&ls[0][r2 * 32 + s2 * 8]);
        uint4 u2   = *(const uint4*)(&ls[1][r2 * 32 + s2 * 8]);
        f16x8 a1im = __builtin_bit_cast(f16x8, u1);
        f16x8 a2im = __builtin_bit_cast(f16x8, u2);
        uint4 n1 = make_uint4(u1.x ^ 0x80008000u, u1.y ^ 0x80008000u,
                              u1.z ^ 0x80008000u, u1.w ^ 0x80008000u);
        uint4 n2 = make_uint4(u2.x ^ 0x80008000u, u2.y ^ 0x80008000u,
                              u2.z ^ 0x80008000u, u2.w ^ 0x80008000u);
        f16x8 na1 = __builtin_bit_cast(f16x8, n1);
        f16x8 na2 = __builtin_bit_cast(f16x8, n2);

#pragma unroll
        for (int j = 0; j < 16; ++j) {
            int rb = 16 * j + lr;
            int sb = lk ^ ((rb >> 1) & 3);
            f16x8 bre = *(const f16x8*)(&ls[0][rb * 32 + sb * 8]);
            f16x8 bim = *(const f16x8*)(&ls[1][rb * 32 + sb * 8]);
            cR[j] = __builtin_amdgcn_mfma_f32_16x16x32_f16(a1re, bre, cR[j], 0, 0, 0);
            cR[j] = __builtin_amdgcn_mfma_f32_16x16x32_f16(a1im, bim, cR[j], 0, 0, 0);
            cI[j] = __builtin_amdgcn_mfma_f32_16x16x32_f16(a1re, bim, cI[j], 0, 0, 0);
            cI[j] = __builtin_amdgcn_mfma_f32_16x16x32_f16(na1,  bre, cI[j], 0, 0, 0);
            if (j >= 8) {
                dR[j-8] = __builtin_amdgcn_mfma_f32_16x16x32_f16(a2re, bre, dR[j-8], 0, 0, 0);
                dR[j-8] = __builtin_amdgcn_mfma_f32_16x16x32_f16(a2im, bim, dR[j-8], 0, 0, 0);
                dI[j-8] = __builtin_amdgcn_mfma_f32_16x16x32_f16(a2re, bim, dI[j-8], 0, 0, 0);
                dI[j-8] = __builtin_amdgcn_mfma_f32_16x16x32_f16(na2,  bre, dI[j-8], 0, 0, 0);
            }
        }
    }

    f16* oR = AhAre + (size_t)b * 65536;
    f16* oI = AhAim + (size_t)b * 65536;

    // direct epilogue: rows 16g (all cols), rows 128+16g (cols 128..255)
#pragma unroll
    for (int j = 0; j < 16; ++j)
#pragma unroll
        for (int r = 0; r < 4; ++r) {
            int n = 16 * g + lk * 4 + r;
            int c = 16 * j + lr;
            oR[(size_t)n * 256 + c] = (f16)cR[j][r];
            oI[(size_t)n * 256 + c] = (f16)cI[j][r];
        }
#pragma unroll
    for (int j = 0; j < 8; ++j)
#pragma unroll
        for (int r = 0; r < 4; ++r) {
            int n = 128 + 16 * g + lk * 4 + r;
            int c = 128 + 16 * j + lr;
            oR[(size_t)n * 256 + c] = (f16)dR[j][r];
            oI[(size_t)n * 256 + c] = (f16)dI[j][r];
        }

    // Hermitian mirror: q3[128+jj][nn] = conj(q1[nn][128+jj]); q1 = cR/cI[j>=8]
    f16* lsm = &ls[0][0];                       // reuse 32KB as [128][128]
    const int jj_out = tid >> 2, qtr = tid & 3; // 128 rows x 4 thread-quarters

    __syncthreads();                            // last ls MFMA reads done
    // Re plane: copy
#pragma unroll
    for (int j = 8; j < 16; ++j)
#pragma unroll
        for (int r = 0; r < 4; ++r) {
            int jj = 16 * (j - 8) + lr;
            int nn = 16 * g + lk * 4 + r;
            lsm[jj * 128 + nn] = (f16)cR[j][r];
        }
    __syncthreads();
    {
        const f16* srow = lsm + jj_out * 128 + qtr * 32;
        f16* drow = oR + (size_t)(128 + jj_out) * 256 + qtr * 32;
#pragma unroll
        for (int ch = 0; ch < 4; ++ch)
            *(uint4*)(void*)(drow + ch * 8) = *(const uint4*)(srow + ch * 8);
    }
    __syncthreads();
    // Im plane: negate
#pragma unroll
    for (int j = 8; j < 16; ++j)
#pragma unroll
        for (int r = 0; r < 4; ++r) {
            int jj = 16 * (j - 8) + lr;
            int nn = 16 * g + lk * 4 + r;
            lsm[jj * 128 + nn] = (f16)(-cI[j][r]);
        }
    __syncthreads();
    {
        const f16* srow = lsm + jj_out * 128 + qtr * 32;
        f16* drow = oI + (size_t)(128 + jj_out) * 256 + qtr * 32;
#pragma unroll
        for (int ch = 0; ch < 4; ++ch)
            *(uint4*)(void*)(drow + ch * 8) = *(const uint4*)(srow + ch * 8);
    }
}

// ---------------------------------------------------------------------------
// Kernel 2: power iteration, 8-WAVE / 32-ROWS-PER-WAVE form (unchanged from
// r6: 60 -> ~28us there).  Deferred normalization (stable form).
// ---------------------------------------------------------------------------
static __device__ __forceinline__ void matvec2(const f16x8 (&afr)[2][16],
                                               const f16* __restrict__ vs, int h,
                                               float4 (&y)[2]) {
    f16x8 bf[16];
#pragma unroll
    for (int c = 0; c < 16; ++c) bf[c] = *(const f16x8*)(vs + 32 * c + 8 * h);
    f32x4 P0[2], P1[2];
#pragma unroll
    for (int rg = 0; rg < 2; ++rg) { P0[rg] = (f32x4)0.0f; P1[rg] = (f32x4)0.0f; }
#pragma unroll
    for (int c = 0; c < 16; ++c) {
#pragma unroll
        for (int rg = 0; rg < 2; ++rg) {
            if (c & 1) P1[rg] = __builtin_amdgcn_mfma_f32_16x16x32_f16(afr[rg][c], bf[c], P1[rg], 0, 0, 0);
            else       P0[rg] = __builtin_amdgcn_mfma_f32_16x16x32_f16(afr[rg][c], bf[c], P0[rg], 0, 0, 0);
        }
    }
#pragma unroll
    for (int rg = 0; rg < 2; ++rg)
        y[rg] = make_float4(P0[rg][0] + P1[rg][0], P0[rg][1] + P1[rg][1],
                            P0[rg][2] + P1[rg][2], P0[rg][3] + P1[rg][3]);
}

__global__ __launch_bounds__(512, 2) void k_power(const f16* __restrict__ AhAre,
                                                  const f16* __restrict__ AhAim,
                                                  const float* __restrict__ vre,
                                                  const float* __restrict__ vim,
                                                  const int* __restrict__ pniter,
                                                  float* __restrict__ out) {
    const int tid = threadIdx.x;
    const int b = blockIdx.x;
    const int l = tid & 63;            // lane
    const int g = tid >> 6;            // wave 0..7
    const int sel = l & 15;            // A-row-within-group / B-col
    const int h = l >> 4;              // k-slot 0..3

    __shared__ __align__(16) f16 v0h[2][512];   // [buf][ vr ; -vi ]
    __shared__ __align__(16) f16 v1h[2][512];   // [buf][ vi ;  vr ]
    __shared__ __align__(16) float part[2][8];

    // ---- load A fragments: wave g owns rows 32g .. 32g+31 (2 row-groups)
    f16x8 afr[2][16];
#pragma unroll
    for (int rg = 0; rg < 2; ++rg) {
        const int m = 32 * g + 16 * rg + sel;
        const f16* bR = AhAre + (size_t)b * 65536 + (size_t)m * 256 + 8 * h;
        const f16* bI = AhAim + (size_t)b * 65536 + (size_t)m * 256 + 8 * h;
#pragma unroll
        for (int c = 0; c < 8; ++c) {
            afr[rg][c]     = *(const f16x8*)(bR + 32 * c);
            afr[rg][8 + c] = *(const f16x8*)(bI + 32 * c);
        }
    }
#pragma unroll
    for (int rg = 0; rg < 2; ++rg)
#pragma unroll
        for (int c = 0; c < 16; ++c) asm volatile("" : "+a"(afr[rg][c]));

    if (tid < 256) {
        float xr = vre[b * 256 + tid], xi = vim[b * 256 + tid];
        v0h[0][tid]       = (f16)xr;
        v0h[0][256 + tid] = (f16)(-xi);
        v1h[0][tid]       = (f16)xi;
        v1h[0][256 + tid] = (f16)xr;
    }
    __syncthreads();

    const int niter = *pniter;
    const f16* vsel = (sel == 0) ? &v0h[0][0] : &v1h[0][0];

    float eig = 0.0f;

    auto npart = [&](int wb, const float4 (&y)[2]) {
        float s_ = 0.0f;
        if (sel < 2) {
#pragma unroll
            for (int rg = 0; rg < 2; ++rg)
                s_ += y[rg].x * y[rg].x + y[rg].y * y[rg].y
                    + y[rg].z * y[rg].z + y[rg].w * y[rg].w;
        }
        s_ += __shfl_xor(s_, 1, 64);
        s_ += __shfl_xor(s_, 16, 64);
        s_ += __shfl_xor(s_, 32, 64);
        if (l == 0) part[wb][g] = s_;
    };
    auto vwrite = [&](int wb, const float4 (&y)[2], float sc) {
        if (sel < 2) {
#pragma unroll
            for (int rg = 0; rg < 2; ++rg) {
                uint32_t w0 = pack2(y[rg].x * sc, y[rg].y * sc);
                uint32_t w1 = pack2(y[rg].z * sc, y[rg].w * sc);
                int m0 = 32 * g + 16 * rg + 4 * h;    // 4 consecutive rows
                if (sel == 0) {                       // y = new vr
                    *(uint2*)(void*)(&v0h[wb][m0])       = make_uint2(w0, w1);
                    *(uint2*)(void*)(&v1h[wb][256 + m0]) = make_uint2(w0, w1);
                } else {                              // y = new vi
                    *(uint2*)(void*)(&v1h[wb][m0])       = make_uint2(w0, w1);
                    *(uint2*)(void*)(&v0h[wb][256 + m0]) =
                        make_uint2(w0 ^ 0x80008000u, w1 ^ 0x80008000u);
                }
            }
        }
    };
    auto psum = [&](int rb) -> float {
        float4 q0 = *(const float4*)(&part[rb][0]);
        float4 q1 = *(const float4*)(&part[rb][4]);
        return (q0.x + q0.y + q0.z + q0.w) + (q1.x + q1.y + q1.z + q1.w);
    };

    float sc_m1 = 1.0f;   // s_{t-1}
    float nm2   = 1.0f;   // n_{t-2}

    float4 y[2];

    // ---- peeled iteration 1 (synchronous): u_1 = y_1/e_1, n_1 = 1 ----
    if (niter >= 1) {
        matvec2(afr, vsel, h, y);
        npart(1, y);
        __syncthreads();
        float e1v = sqrtf(psum(1));
        float sc  = __builtin_amdgcn_rcpf(e1v + 1e-6f);
        vwrite(1, y, sc);
        eig = e1v;
        __syncthreads();
    }
    // ---- peeled iteration 2 (synchronous): u_2 = y_2/e_2, n_2 = 1 ----
    if (niter >= 2) {
        matvec2(afr, vsel + 512, h, y);
        npart(0, y);
        __syncthreads();
        float e2v = sqrtf(psum(0));
        float sc  = __builtin_amdgcn_rcpf(e2v + 1e-6f);
        vwrite(0, y, sc);
        eig = e2v;
        sc_m1 = sc;   // s_2
        nm2   = 1.0f; // n_1
        __syncthreads();
    }

    // ---- pipelined iterations 3..niter: one barrier each ----
    int wr = 0;
    for (int t = 3; t <= niter; ++t) {
        const int rd = wr;    // buffer holding u_{t-1}, part[rd] = q_{t-1}
        wr ^= 1;
        float q   = psum(rd);                                  // ||y_{t-1}||^2
        float e1v = __builtin_amdgcn_sqrtf(q);                 // e_{t-1}
        float nm1 = e1v * sc_m1;                               // n_{t-1}
        float sc  = nm2 * __builtin_amdgcn_rcpf(e1v * nm1 + 1e-12f);  // s_t
        matvec2(afr, vsel + (size_t)rd * 512, h, y);           // y_t
        vwrite(wr, y, sc);
        npart(wr, y);
        nm2 = nm1; sc_m1 = sc;
        __syncthreads();
    }

    // ---- epilogue: exact eig = ||y_T|| / n_{T-1}
    if (niter >= 3) {
        float qT = psum(wr);
        eig = sqrtf(qT) / (nm2 + 1e-12f);
    }
    if (tid == 0) out[b] = eig;
}

extern "C" void kernel_launch(void* const* d_in, const int* in_sizes, int n_in,
                              void* d_out, int out_size, void* d_ws, size_t ws_size,
                              hipStream_t stream) {
    const float* Are = (const float*)d_in[0];
    const float* Aim = (const float*)d_in[1];
    const float* vre = (const float*)d_in[2];
    const float* vim = (const float*)d_in[3];
    const int* niter = (const int*)d_in[4];
    float* out = (float*)d_out;

    f16* AhAre = (f16*)d_ws;                                            // 32 MB
    f16* AhAim = (f16*)((char*)d_ws + (size_t)32 * 1024 * 1024);        // 32 MB

    k_gemm<<<dim3(256), dim3(512), 0, stream>>>(Are, Aim, AhAre, AhAim);
    k_power<<<dim3(256), dim3(512), 0, stream>>>(AhAre, AhAim, vre, vim, niter, out);
}